// Round 1
// baseline (3688.850 us; speedup 1.0000x reference)
//
#include <hip/hip_runtime.h>

// PointVoxelCNN fused pipeline for MI355X (gfx950).
// B=8, N=32768, C=Cin=64, R=32, G=32 (2 channels/group).
// Strategy: conv3d as 27 shifted 64x64x64 MFMA GEMM steps, bf16 hi/lo split
// (3-pass) for fp32-quality accuracy; everything else fp32 VALU.

#define R3_ 32768
#define RSQRT2 0.70710678118654752440f

typedef float f32x4 __attribute__((ext_vector_type(4)));
typedef __bf16 bf16x8 __attribute__((ext_vector_type(8)));

static __device__ __forceinline__ unsigned short f2bf(float x) {
    union { float f; unsigned u; } v; v.f = x;
    unsigned r = v.u + 0x7FFFu + ((v.u >> 16) & 1u);
    return (unsigned short)(r >> 16);
}
static __device__ __forceinline__ float bf2f(unsigned short b) {
    union { unsigned u; float f; } v; v.u = ((unsigned)b) << 16; return v.f;
}
static __device__ __forceinline__ float leaky(float x) { return x >= 0.f ? x : 0.01f * x; }

// ---------------- weight transform: w[O][I][27] f32 -> wt[ko][co][ci] bf16 hi/lo
__global__ __launch_bounds__(256) void wt_transform(const float* __restrict__ w,
                                                    unsigned short* __restrict__ hi,
                                                    unsigned short* __restrict__ lo) {
    int idx = blockIdx.x * 256 + threadIdx.x;    // 27*64*64 = 110592
    int ko = idx >> 12;
    int co = (idx >> 6) & 63;
    int ci = idx & 63;
    float v = w[(co * 64 + ci) * 27 + ko];
    unsigned short h = f2bf(v);
    hi[idx] = h;
    lo[idx] = f2bf(v - bf2f(h));
}

// ---------------- voxelize: trilinear scatter with f32 atomics
__global__ __launch_bounds__(256) void voxelize_k(const float* __restrict__ pts,
                                                  const float* __restrict__ feat,
                                                  float* __restrict__ vox,
                                                  float* __restrict__ cnt) {
    int tid = threadIdx.x;
    int c = tid & 63;
    int p = blockIdx.x * 4 + (tid >> 6);         // global point id (b*N+n)
    const float* P = pts + (size_t)p * 3;
    float cx = fminf(fmaxf((P[0] + 1.f) * 15.5f, 0.f), 31.f);
    float cy = fminf(fmaxf((P[1] + 1.f) * 15.5f, 0.f), 31.f);
    float cz = fminf(fmaxf((P[2] + 1.f) * 15.5f, 0.f), 31.f);
    int lx = (int)cx; if (lx > 30) lx = 30; float fx = cx - (float)lx;
    int ly = (int)cy; if (ly > 30) ly = 30; float fy = cy - (float)ly;
    int lz = (int)cz; if (lz > 30) lz = 30; float fz = cz - (float)lz;
    int bb = p >> 15;
    int base3 = (lx * 32 + ly) * 32 + lz;
    float f = feat[((size_t)p << 6) + c];
    float* vbase = vox + (((size_t)bb) << 21);
#pragma unroll
    for (int cr = 0; cr < 8; ++cr) {
        int di = cr >> 2, dj = (cr >> 1) & 1, dk = cr & 1;
        float w = (di ? fx : 1.f - fx) * (dj ? fy : 1.f - fy) * (dk ? fz : 1.f - fz);
        int fl = base3 + di * 1024 + dj * 32 + dk;
        atomicAdd(vbase + (((size_t)fl) << 6) + c, w * f);
    }
    if (c < 8) {
        int di = c >> 2, dj = (c >> 1) & 1, dk = c & 1;
        float w = (di ? fx : 1.f - fx) * (dj ? fy : 1.f - fy) * (dk ? fz : 1.f - fz);
        int fl = base3 + di * 1024 + dj * 32 + dk;
        atomicAdd(cnt + (((size_t)bb) << 15) + fl, w);
    }
}

// ---------------- normalize (optional) + per-channel partial sums for GN stats
__global__ __launch_bounds__(256) void norm_stats(const float* __restrict__ src,
                                                  const float* __restrict__ cnt,
                                                  float* __restrict__ dst,
                                                  float* __restrict__ chsum) {
    __shared__ float rs[256], rq[256];
    int b = blockIdx.y;
    int tid = threadIdx.x;
    int c = tid & 63, rsub = tid >> 6;
    size_t rowb = ((size_t)b << 15) + (size_t)blockIdx.x * 256;
    float s = 0.f, q = 0.f;
    for (int i = 0; i < 64; ++i) {
        size_t row = rowb + rsub + i * 4;
        size_t idx = (row << 6) + c;
        float v = src[idx];
        if (cnt) { v = v / fmaxf(cnt[row], 1e-8f); dst[idx] = v; }
        s += v; q += v * v;
    }
    rs[tid] = s; rq[tid] = q;
    __syncthreads();
    if (tid < 64) {
        s = rs[tid] + rs[tid + 64] + rs[tid + 128] + rs[tid + 192];
        q = rq[tid] + rq[tid + 64] + rq[tid + 128] + rq[tid + 192];
        atomicAdd(&chsum[((b << 6) + tid) * 2], s);
        atomicAdd(&chsum[((b << 6) + tid) * 2 + 1], q);
    }
}

// ---------------- finalize GN stats: chsum[b][64][2] -> musr[b][32][2] (mu, rstd)
__global__ void gn_finalize(const float* __restrict__ chsum, float* __restrict__ musr) {
    int t = threadIdx.x;              // 256 = 8 b * 32 g
    int b = t >> 5, g = t & 31;
    float s = chsum[((b << 6) + 2 * g) * 2] + chsum[((b << 6) + 2 * g + 1) * 2];
    float q = chsum[((b << 6) + 2 * g) * 2 + 1] + chsum[((b << 6) + 2 * g + 1) * 2 + 1];
    float mu = s * (1.f / 65536.f);
    float var = q * (1.f / 65536.f) - mu * mu;
    musr[t * 2] = mu;
    musr[t * 2 + 1] = rsqrtf(var + 1e-5f);
}

// ---------------- GN apply + leaky -> bf16 hi/lo activation planes
__global__ __launch_bounds__(256) void gn_apply(const float* __restrict__ src,
                                                const float* __restrict__ musr,
                                                const float* __restrict__ gamma,
                                                const float* __restrict__ beta,
                                                unsigned short* __restrict__ hi,
                                                unsigned short* __restrict__ lo) {
    int i4 = blockIdx.x * 256 + threadIdx.x;     // B*R3*16
    int row = i4 >> 4;
    int b = row >> 15;
    int c0 = (i4 & 15) << 2;
    const float4 x = *(const float4*)(src + ((size_t)i4 << 2));
    float xs[4] = {x.x, x.y, x.z, x.w};
    unsigned short hs[4], ls[4];
#pragma unroll
    for (int j = 0; j < 4; ++j) {
        int c = c0 + j;
        int g = c >> 1;
        float mu = musr[((b << 5) + g) * 2];
        float rstd = musr[((b << 5) + g) * 2 + 1];
        float y = (xs[j] - mu) * rstd * gamma[c] + beta[c];
        y = leaky(y);
        hs[j] = f2bf(y);
        ls[j] = f2bf(y - bf2f(hs[j]));
    }
    ushort4 H; H.x = hs[0]; H.y = hs[1]; H.z = hs[2]; H.w = hs[3];
    ushort4 L; L.x = ls[0]; L.y = ls[1]; L.z = ls[2]; L.w = ls[3];
    *(ushort4*)(hi + ((size_t)i4 << 2)) = H;
    *(ushort4*)(lo + ((size_t)i4 << 2)) = L;
}

// ---------------- conv3d 3x3x3 SAME, 64->64ch, bf16 hi/lo 3-pass MFMA
// block: 256 thr (4 waves), tile = 64 voxels (2d x 4h x 8w) x 64 cout.
// K-loop over 27 taps; per tap stage shifted A[64 vox][64 ci] and W[64 co][64 ci]
// (hi+lo planes) into LDS with XOR swizzle (rows stride 128B).
__global__ __launch_bounds__(256) void conv3d_k(const unsigned short* __restrict__ Ah,
                                                const unsigned short* __restrict__ Al,
                                                const unsigned short* __restrict__ Wh,
                                                const unsigned short* __restrict__ Wl,
                                                const float* __restrict__ bias,
                                                const float* __restrict__ skip,
                                                float* __restrict__ out) {
    __shared__ unsigned short sAh[4096], sAl[4096], sBh[4096], sBl[4096];   // 8KB each
    int tid = threadIdx.x;
    int lane = tid & 63, wave = tid >> 6;
    int b = blockIdx.y;
    int t = blockIdx.x;                 // 512 tiles: 16d * 8h * 4w
    int tw = t & 3, th = (t >> 2) & 7, td = t >> 5;
    int d0 = td << 1, h0 = th << 2, w0 = tw << 3;

    f32x4 acc[4] = {};

    int kg = lane >> 4;
    int arow = (wave << 4) | (lane & 15);
    int aoff = (arow << 7) + (kg << 4);
    int aswz = (arow & 7) << 4;

    for (int ko = 0; ko < 27; ++ko) {
        int di = ko / 9, rem = ko - di * 9;
        int dj = rem / 3, dk = rem - dj * 3;
        int4 ar[2][2], br[2][2];
#pragma unroll
        for (int s = 0; s < 2; ++s) {
            int chunk = tid + (s << 8);
            int row = chunk >> 3, ci0 = (chunk & 7) << 3;
            int d = row >> 5, h = (row >> 3) & 3, w = row & 7;
            int gd = d0 + d + di - 1, gh = h0 + h + dj - 1, gw = w0 + w + dk - 1;
            bool ok = ((unsigned)gd < 32u) && ((unsigned)gh < 32u) && ((unsigned)gw < 32u);
            size_t gi = ((((size_t)b << 15) + (size_t)((gd << 10) + (gh << 5) + gw)) << 6) + ci0;
            int4 z = {0, 0, 0, 0};
            ar[s][0] = ok ? *(const int4*)(Ah + gi) : z;
            ar[s][1] = ok ? *(const int4*)(Al + gi) : z;
            size_t wi = (((size_t)ko) << 12) + (row << 6) + ci0;
            br[s][0] = *(const int4*)(Wh + wi);
            br[s][1] = *(const int4*)(Wl + wi);
        }
        __syncthreads();    // previous iteration's LDS reads complete
#pragma unroll
        for (int s = 0; s < 2; ++s) {
            int chunk = tid + (s << 8);
            int row = chunk >> 3, ci0 = (chunk & 7) << 3;
            int lb = ((row << 7) + (ci0 << 1)) ^ ((row & 7) << 4);
            *(int4*)((char*)sAh + lb) = ar[s][0];
            *(int4*)((char*)sAl + lb) = ar[s][1];
            *(int4*)((char*)sBh + lb) = br[s][0];
            *(int4*)((char*)sBl + lb) = br[s][1];
        }
        __syncthreads();    // staging visible

        bf16x8 ah0 = *(const bf16x8*)((const char*)sAh + (aoff ^ aswz));
        bf16x8 ah1 = *(const bf16x8*)((const char*)sAh + ((aoff + 64) ^ aswz));
        bf16x8 al0 = *(const bf16x8*)((const char*)sAl + (aoff ^ aswz));
        bf16x8 al1 = *(const bf16x8*)((const char*)sAl + ((aoff + 64) ^ aswz));
#pragma unroll
        for (int nf = 0; nf < 4; ++nf) {
            int bco = (nf << 4) | (lane & 15);
            int boff = (bco << 7) + (kg << 4);
            int bswz = (bco & 7) << 4;
            bf16x8 bh0 = *(const bf16x8*)((const char*)sBh + (boff ^ bswz));
            bf16x8 bh1 = *(const bf16x8*)((const char*)sBh + ((boff + 64) ^ bswz));
            bf16x8 bl0 = *(const bf16x8*)((const char*)sBl + (boff ^ bswz));
            bf16x8 bl1 = *(const bf16x8*)((const char*)sBl + ((boff + 64) ^ bswz));
            acc[nf] = __builtin_amdgcn_mfma_f32_16x16x32_bf16(ah0, bh0, acc[nf], 0, 0, 0);
            acc[nf] = __builtin_amdgcn_mfma_f32_16x16x32_bf16(ah1, bh1, acc[nf], 0, 0, 0);
            acc[nf] = __builtin_amdgcn_mfma_f32_16x16x32_bf16(ah0, bl0, acc[nf], 0, 0, 0);
            acc[nf] = __builtin_amdgcn_mfma_f32_16x16x32_bf16(ah1, bl1, acc[nf], 0, 0, 0);
            acc[nf] = __builtin_amdgcn_mfma_f32_16x16x32_bf16(al0, bh0, acc[nf], 0, 0, 0);
            acc[nf] = __builtin_amdgcn_mfma_f32_16x16x32_bf16(al1, bh1, acc[nf], 0, 0, 0);
        }
    }
    // epilogue: D layout col=lane&15 (co), row=(lane>>4)*4+reg (voxel in wave tile)
    bool has_skip = (skip != nullptr);
#pragma unroll
    for (int nf = 0; nf < 4; ++nf) {
        int co = (nf << 4) | (lane & 15);
        float bv = bias[co];
#pragma unroll
        for (int r = 0; r < 4; ++r) {
            int vrow = (wave << 4) + (kg << 2) + r;
            int d = vrow >> 5, h = (vrow >> 3) & 3, w = vrow & 7;
            size_t oi = ((((size_t)b << 15) +
                          (size_t)(((d0 + d) << 10) + ((h0 + h) << 5) + (w0 + w))) << 6) + co;
            float v = acc[nf][r] + bv;
            if (has_skip) v = (v + skip[oi]) * RSQRT2;
            out[oi] = v;
        }
    }
}

// ---------------- fused point MLP + devoxelize + final combine
__global__ __launch_bounds__(256) void point_devox(const float* __restrict__ pts,
                                                   const float* __restrict__ feat,
                                                   const float* __restrict__ w_pi, const float* __restrict__ b_pi,
                                                   const float* __restrict__ w_p1, const float* __restrict__ b_p1,
                                                   const float* __restrict__ w_p2, const float* __restrict__ b_p2,
                                                   const float* __restrict__ grid, float* __restrict__ out) {
    __shared__ float sA[64][64];
    __shared__ float sF0[64][64];
    __shared__ int   sFl[64][8];
    __shared__ float sWt[64][8];
    int tid = threadIdx.x;
    int c = tid & 63, ps = tid >> 6;
    size_t pbase = (size_t)blockIdx.x * 64;
    int b = (int)(pbase >> 15);
#pragma unroll
    for (int i = 0; i < 16; ++i) {
        int p = ps + i * 4;
        sA[p][c] = feat[((pbase + p) << 6) + c];
    }
    if (tid < 64) {
        const float* P = pts + (pbase + tid) * 3;
        float cx = fminf(fmaxf((P[0] + 1.f) * 15.5f, 0.f), 31.f);
        float cy = fminf(fmaxf((P[1] + 1.f) * 15.5f, 0.f), 31.f);
        float cz = fminf(fmaxf((P[2] + 1.f) * 15.5f, 0.f), 31.f);
        int lx = (int)cx; if (lx > 30) lx = 30; float fx = cx - (float)lx;
        int ly = (int)cy; if (ly > 30) ly = 30; float fy = cy - (float)ly;
        int lz = (int)cz; if (lz > 30) lz = 30; float fz = cz - (float)lz;
        int base3 = (lx * 32 + ly) * 32 + lz;
#pragma unroll
        for (int cr = 0; cr < 8; ++cr) {
            int di = cr >> 2, dj = (cr >> 1) & 1, dk = cr & 1;
            sFl[tid][cr] = base3 + di * 1024 + dj * 32 + dk;
            sWt[tid][cr] = (di ? fx : 1.f - fx) * (dj ? fy : 1.f - fy) * (dk ? fz : 1.f - fz);
        }
    }
    __syncthreads();

    float wreg[64], acc[16];
    // ---- layer 1: f0 = feat @ w_pi + b_pi
#pragma unroll
    for (int k = 0; k < 64; ++k) wreg[k] = w_pi[k * 64 + c];
    float bv = b_pi[c];
#pragma unroll
    for (int i = 0; i < 16; ++i) {
        int p = ps + i * 4;
        float a = bv;
#pragma unroll
        for (int k4 = 0; k4 < 16; ++k4) {
            float4 x = *(const float4*)&sA[p][k4 << 2];
            a += x.x * wreg[k4 * 4] + x.y * wreg[k4 * 4 + 1] + x.z * wreg[k4 * 4 + 2] + x.w * wreg[k4 * 4 + 3];
        }
        acc[i] = a;
    }
    __syncthreads();
#pragma unroll
    for (int i = 0; i < 16; ++i) { int p = ps + i * 4; sF0[p][c] = acc[i]; sA[p][c] = leaky(acc[i]); }
    __syncthreads();
    // ---- layer 2
#pragma unroll
    for (int k = 0; k < 64; ++k) wreg[k] = w_p1[k * 64 + c];
    bv = b_p1[c];
#pragma unroll
    for (int i = 0; i < 16; ++i) {
        int p = ps + i * 4;
        float a = bv;
#pragma unroll
        for (int k4 = 0; k4 < 16; ++k4) {
            float4 x = *(const float4*)&sA[p][k4 << 2];
            a += x.x * wreg[k4 * 4] + x.y * wreg[k4 * 4 + 1] + x.z * wreg[k4 * 4 + 2] + x.w * wreg[k4 * 4 + 3];
        }
        acc[i] = a;
    }
    __syncthreads();
#pragma unroll
    for (int i = 0; i < 16; ++i) { int p = ps + i * 4; sA[p][c] = leaky(acc[i]); }
    __syncthreads();
    // ---- layer 3 + point skip
#pragma unroll
    for (int k = 0; k < 64; ++k) wreg[k] = w_p2[k * 64 + c];
    bv = b_p2[c];
#pragma unroll
    for (int i = 0; i < 16; ++i) {
        int p = ps + i * 4;
        float a = bv;
#pragma unroll
        for (int k4 = 0; k4 < 16; ++k4) {
            float4 x = *(const float4*)&sA[p][k4 << 2];
            a += x.x * wreg[k4 * 4] + x.y * wreg[k4 * 4 + 1] + x.z * wreg[k4 * 4 + 2] + x.w * wreg[k4 * 4 + 3];
        }
        acc[i] = (a + sF0[p][c]) * RSQRT2;   // pts
    }
    // ---- devoxelize gather + final combine
    const float* gb = grid + (((size_t)b) << 21);
#pragma unroll
    for (int i = 0; i < 16; ++i) {
        int p = ps + i * 4;
        float dev = 0.f;
#pragma unroll
        for (int cr = 0; cr < 8; ++cr) {
            dev += sWt[p][cr] * gb[(((size_t)sFl[p][cr]) << 6) + c];
        }
        out[((pbase + p) << 6) + c] = (acc[i] + dev) * RSQRT2;
    }
}

// ---------------- workspace layout (bytes) — total ~194 MiB
constexpr size_t OFF_VOX = 0;                          // f32 [8][32768][64]
constexpr size_t OFF_CNT = 67108864;                   // f32 [8][32768]
constexpr size_t OFF_GBUF = OFF_CNT + 1048576;         // f32 [8][32768][64]
constexpr size_t OFF_AHI = OFF_GBUF + 67108864;        // bf16 [8][32768][64]
constexpr size_t OFF_ALO = OFF_AHI + 33554432;
constexpr size_t OFF_W1H = OFF_ALO + 33554432;         // bf16 [27][64][64]
constexpr size_t OFF_W1L = OFF_W1H + 262144;
constexpr size_t OFF_W2H = OFF_W1L + 262144;
constexpr size_t OFF_W2L = OFF_W2H + 262144;
constexpr size_t OFF_CS1 = OFF_W2L + 262144;           // f32 [8][64][2]
constexpr size_t OFF_CS2 = OFF_CS1 + 4096;
constexpr size_t OFF_MS1 = OFF_CS2 + 4096;             // f32 [8][32][2]
constexpr size_t OFF_MS2 = OFF_MS1 + 2048;

extern "C" void kernel_launch(void* const* d_in, const int* in_sizes, int n_in,
                              void* d_out, int out_size, void* d_ws, size_t ws_size,
                              hipStream_t stream) {
    const float* points = (const float*)d_in[0];
    const float* feat   = (const float*)d_in[1];
    const float* w_pi = (const float*)d_in[2];
    const float* b_pi = (const float*)d_in[3];
    const float* w_p1 = (const float*)d_in[4];
    const float* b_p1 = (const float*)d_in[5];
    const float* w_p2 = (const float*)d_in[6];
    const float* b_p2 = (const float*)d_in[7];
    const float* g1   = (const float*)d_in[8];
    const float* be1  = (const float*)d_in[9];
    const float* w_c1 = (const float*)d_in[10];
    const float* b_c1 = (const float*)d_in[11];
    const float* g2   = (const float*)d_in[12];
    const float* be2  = (const float*)d_in[13];
    const float* w_c2 = (const float*)d_in[14];
    const float* b_c2 = (const float*)d_in[15];

    char* ws = (char*)d_ws;
    float* vox  = (float*)(ws + OFF_VOX);
    float* cnt  = (float*)(ws + OFF_CNT);
    float* gbuf = (float*)(ws + OFF_GBUF);
    unsigned short* ahi = (unsigned short*)(ws + OFF_AHI);
    unsigned short* alo = (unsigned short*)(ws + OFF_ALO);
    unsigned short* w1h = (unsigned short*)(ws + OFF_W1H);
    unsigned short* w1l = (unsigned short*)(ws + OFF_W1L);
    unsigned short* w2h = (unsigned short*)(ws + OFF_W2H);
    unsigned short* w2l = (unsigned short*)(ws + OFF_W2L);
    float* cs1 = (float*)(ws + OFF_CS1);
    float* cs2 = (float*)(ws + OFF_CS2);
    float* ms1 = (float*)(ws + OFF_MS1);
    float* ms2 = (float*)(ws + OFF_MS2);

    hipMemsetAsync(ws, 0, OFF_GBUF, stream);                   // vox + cnt
    hipMemsetAsync(ws + OFF_CS1, 0, 12288, stream);            // stat buffers

    wt_transform<<<432, 256, 0, stream>>>(w_c1, w1h, w1l);
    wt_transform<<<432, 256, 0, stream>>>(w_c2, w2h, w2l);

    voxelize_k<<<65536, 256, 0, stream>>>(points, feat, vox, cnt);
    norm_stats<<<dim3(128, 8), 256, 0, stream>>>(vox, cnt, vox, cs1);
    gn_finalize<<<1, 256, 0, stream>>>(cs1, ms1);
    gn_apply<<<16384, 256, 0, stream>>>(vox, ms1, g1, be1, ahi, alo);
    conv3d_k<<<dim3(512, 8), 256, 0, stream>>>(ahi, alo, w1h, w1l, b_c1, nullptr, gbuf);
    norm_stats<<<dim3(128, 8), 256, 0, stream>>>(gbuf, nullptr, nullptr, cs2);
    gn_finalize<<<1, 256, 0, stream>>>(cs2, ms2);
    gn_apply<<<16384, 256, 0, stream>>>(gbuf, ms2, g2, be2, ahi, alo);
    conv3d_k<<<dim3(512, 8), 256, 0, stream>>>(ahi, alo, w2h, w2l, b_c2, vox, gbuf);
    point_devox<<<4096, 256, 0, stream>>>(points, feat, w_pi, b_pi, w_p1, b_p1,
                                          w_p2, b_p2, gbuf, (float*)d_out);
}

// Round 2
// 2247.294 us; speedup vs baseline: 1.6415x; 1.6415x over previous
//
#include <hip/hip_runtime.h>

// PointVoxelCNN fused pipeline for MI355X (gfx950).
// B=8, N=32768, C=Cin=64, R=32, G=32 (2 channels/group).
// Round 2: (1) conv3d rebuilt: M=256-voxel tile, wave tile 64x64 (MFMA:ds_read = 3.0),
// global_load_lds width-16 staging with source-pre-swizzle, 80KB LDS, 2 blocks/CU,
// XCD-swizzled grid (one batch per XCD). (2) voxelize rebuilt: bin+scan+fill+
// region-exclusive LDS accumulate (no global f32 atomics), fused normalize + GN1 stats.

#define RSQRT2 0.70710678118654752440f

typedef float f32x4 __attribute__((ext_vector_type(4)));
typedef __bf16 bf16x8 __attribute__((ext_vector_type(8)));

static __device__ __forceinline__ unsigned short f2bf(float x) {
    union { float f; unsigned u; } v; v.f = x;
    unsigned r = v.u + 0x7FFFu + ((v.u >> 16) & 1u);
    return (unsigned short)(r >> 16);
}
static __device__ __forceinline__ float bf2f(unsigned short b) {
    union { unsigned u; float f; } v; v.u = ((unsigned)b) << 16; return v.f;
}
static __device__ __forceinline__ float leaky(float x) { return x >= 0.f ? x : 0.01f * x; }

static __device__ __forceinline__ void gload_lds16(const void* g, void* l) {
    __builtin_amdgcn_global_load_lds(
        (const __attribute__((address_space(1))) unsigned int*)g,
        (__attribute__((address_space(3))) unsigned int*)l, 16, 0, 0);
}

static __device__ __forceinline__ void corner_setup(float px, float py, float pz,
        int& lx, int& ly, int& lz, float& fx, float& fy, float& fz) {
    float cx = fminf(fmaxf((px + 1.f) * 15.5f, 0.f), 31.f);
    float cy = fminf(fmaxf((py + 1.f) * 15.5f, 0.f), 31.f);
    float cz = fminf(fmaxf((pz + 1.f) * 15.5f, 0.f), 31.f);
    lx = (int)cx; if (lx > 30) lx = 30; fx = cx - (float)lx;
    ly = (int)cy; if (ly > 30) ly = 30; fy = cy - (float)ly;
    lz = (int)cz; if (lz > 30) lz = 30; fz = cz - (float)lz;
}

// ---------------- weight transform: w[O][I][27] f32 -> wt[ko][co][ci] bf16 hi/lo
__global__ __launch_bounds__(256) void wt_transform(const float* __restrict__ w,
                                                    unsigned short* __restrict__ hi,
                                                    unsigned short* __restrict__ lo) {
    int idx = blockIdx.x * 256 + threadIdx.x;    // 27*64*64 = 110592
    int ko = idx >> 12;
    int co = (idx >> 6) & 63;
    int ci = idx & 63;
    float v = w[(co * 64 + ci) * 27 + ko];
    unsigned short h = f2bf(v);
    hi[idx] = h;
    lo[idx] = f2bf(v - bf2f(h));
}

// ---------------- voxelize pass 1: count points per 4x4x4 bin
__global__ __launch_bounds__(256) void bin_count(const float* __restrict__ pts,
                                                 int* __restrict__ cnt) {
    int p = blockIdx.x * 256 + threadIdx.x;      // 262144
    int lx, ly, lz; float fx, fy, fz;
    corner_setup(pts[p * 3], pts[p * 3 + 1], pts[p * 3 + 2], lx, ly, lz, fx, fy, fz);
    int b = p >> 15;
    int bin = (b << 9) | ((lx >> 2) << 6) | ((ly >> 2) << 3) | (lz >> 2);
    atomicAdd(&cnt[bin], 1);
}

// ---------------- voxelize pass 2: exclusive scan of 4096 bins (1 block)
__global__ __launch_bounds__(256) void bin_scan(const int* __restrict__ cnt,
                                                int* __restrict__ start,
                                                int* __restrict__ cursor) {
    __shared__ int part[256];
    int t = threadIdx.x;
    int local[16];
    int s = 0;
#pragma unroll
    for (int i = 0; i < 16; ++i) { local[i] = s; s += cnt[t * 16 + i]; }
    part[t] = s;
    __syncthreads();
    for (int off = 1; off < 256; off <<= 1) {
        int v = (t >= off) ? part[t - off] : 0;
        __syncthreads();
        part[t] += v;
        __syncthreads();
    }
    int base = (t == 0) ? 0 : part[t - 1];
#pragma unroll
    for (int i = 0; i < 16; ++i) {
        int v = base + local[i];
        start[t * 16 + i] = v;
        cursor[t * 16 + i] = v;
    }
    if (t == 255) start[4096] = part[255];
}

// ---------------- voxelize pass 3: scatter point indices into bins
__global__ __launch_bounds__(256) void bin_fill(const float* __restrict__ pts,
                                                int* __restrict__ cursor,
                                                int* __restrict__ idxb) {
    int p = blockIdx.x * 256 + threadIdx.x;
    int lx, ly, lz; float fx, fy, fz;
    corner_setup(pts[p * 3], pts[p * 3 + 1], pts[p * 3 + 2], lx, ly, lz, fx, fy, fz);
    int b = p >> 15;
    int bin = (b << 9) | ((lx >> 2) << 6) | ((ly >> 2) << 3) | (lz >> 2);
    int slot = atomicAdd(&cursor[bin], 1);
    idxb[slot] = p;
}

// ---------------- voxelize pass 4: region-exclusive accumulate + normalize + GN1 stats
// one block per 4x4x4 cell region; gathers from <=8 neighbor bins; no global atomics
// except the tiny per-channel stat sums.
__global__ __launch_bounds__(256) void vox_accum(const float* __restrict__ pts,
                                                 const float* __restrict__ feat,
                                                 const int* __restrict__ start,
                                                 const int* __restrict__ idxb,
                                                 float* __restrict__ vox,
                                                 float* __restrict__ chsum) {
    __shared__ float acc[4096];      // [cell 64][ch 64]
    __shared__ float cw[64];
    __shared__ float rs[256], rq[256];
    int tid = threadIdx.x, lane = tid & 63, wv = tid >> 6;
    int gid = blockIdx.x;            // 4096 = b*512 + r3
    int b = gid >> 9, r3 = gid & 511;
    int rx = r3 >> 6, ry = (r3 >> 3) & 7, rz = r3 & 7;
    int cx0 = rx << 2, cy0 = ry << 2, cz0 = rz << 2;
    for (int i = tid; i < 4096; i += 256) acc[i] = 0.f;
    if (tid < 64) cw[tid] = 0.f;
    __syncthreads();

    for (int nb = 0; nb < 8; ++nb) {
        int bx = rx - 1 + (nb >> 2), by = ry - 1 + ((nb >> 1) & 1), bz = rz - 1 + (nb & 1);
        if (((unsigned)bx > 7u) || ((unsigned)by > 7u) || ((unsigned)bz > 7u)) continue;
        int bin = (b << 9) | (bx << 6) | (by << 3) | bz;
        int s0 = start[bin], s1 = start[bin + 1];
        for (int i = s0 + wv; i < s1; i += 4) {     // waves stripe the bin's points
            int p = idxb[i];
            int lx, ly, lz; float fx, fy, fz;
            corner_setup(pts[p * 3], pts[p * 3 + 1], pts[p * 3 + 2], lx, ly, lz, fx, fy, fz);
            float f = feat[((size_t)p << 6) + lane];
#pragma unroll
            for (int cr = 0; cr < 8; ++cr) {
                int ux = lx + (cr >> 2) - cx0;
                int uy = ly + ((cr >> 1) & 1) - cy0;
                int uz = lz + (cr & 1) - cz0;
                if (((unsigned)ux < 4u) && ((unsigned)uy < 4u) && ((unsigned)uz < 4u)) {
                    float w = ((cr & 4) ? fx : 1.f - fx) * ((cr & 2) ? fy : 1.f - fy)
                            * ((cr & 1) ? fz : 1.f - fz);
                    int cl = (ux << 4) | (uy << 2) | uz;
                    atomicAdd(&acc[(cl << 6) | lane], w * f);
                    if (lane == 0) atomicAdd(&cw[cl], w);
                }
            }
        }
    }
    __syncthreads();
    // normalize + write + per-channel partial sums
    float s = 0.f, q = 0.f;
    for (int c = wv; c < 64; c += 4) {
        float v = acc[(c << 6) | lane] / fmaxf(cw[c], 1e-8f);
        int cxx = cx0 + (c >> 4), cyy = cy0 + ((c >> 2) & 3), czz = cz0 + (c & 3);
        size_t flat = ((size_t)(b << 15)) + (size_t)((cxx << 10) | (cyy << 5) | czz);
        vox[(flat << 6) + lane] = v;
        s += v; q += v * v;
    }
    rs[tid] = s; rq[tid] = q;
    __syncthreads();
    if (tid < 64) {
        s = rs[tid] + rs[tid + 64] + rs[tid + 128] + rs[tid + 192];
        q = rq[tid] + rq[tid + 64] + rq[tid + 128] + rq[tid + 192];
        atomicAdd(&chsum[((b << 6) + tid) * 2], s);
        atomicAdd(&chsum[((b << 6) + tid) * 2 + 1], q);
    }
}

// ---------------- per-channel partial sums for GN2 (reads conv1 output)
__global__ __launch_bounds__(256) void norm_stats(const float* __restrict__ src,
                                                  float* __restrict__ chsum) {
    __shared__ float rs[256], rq[256];
    int b = blockIdx.y;
    int tid = threadIdx.x;
    int c = tid & 63, rsub = tid >> 6;
    size_t rowb = ((size_t)b << 15) + (size_t)blockIdx.x * 256;
    float s = 0.f, q = 0.f;
    for (int i = 0; i < 64; ++i) {
        size_t idx = ((rowb + rsub + i * 4) << 6) + c;
        float v = src[idx];
        s += v; q += v * v;
    }
    rs[tid] = s; rq[tid] = q;
    __syncthreads();
    if (tid < 64) {
        s = rs[tid] + rs[tid + 64] + rs[tid + 128] + rs[tid + 192];
        q = rq[tid] + rq[tid + 64] + rq[tid + 128] + rq[tid + 192];
        atomicAdd(&chsum[((b << 6) + tid) * 2], s);
        atomicAdd(&chsum[((b << 6) + tid) * 2 + 1], q);
    }
}

// ---------------- finalize GN stats: chsum[b][64][2] -> musr[b][32][2] (mu, rstd)
__global__ void gn_finalize(const float* __restrict__ chsum, float* __restrict__ musr) {
    int t = threadIdx.x;              // 256 = 8 b * 32 g
    int b = t >> 5, g = t & 31;
    float s = chsum[((b << 6) + 2 * g) * 2] + chsum[((b << 6) + 2 * g + 1) * 2];
    float q = chsum[((b << 6) + 2 * g) * 2 + 1] + chsum[((b << 6) + 2 * g + 1) * 2 + 1];
    float mu = s * (1.f / 65536.f);
    float var = q * (1.f / 65536.f) - mu * mu;
    musr[t * 2] = mu;
    musr[t * 2 + 1] = rsqrtf(var + 1e-5f);
}

// ---------------- GN apply + leaky -> bf16 hi/lo activation planes
__global__ __launch_bounds__(256) void gn_apply(const float* __restrict__ src,
                                                const float* __restrict__ musr,
                                                const float* __restrict__ gamma,
                                                const float* __restrict__ beta,
                                                unsigned short* __restrict__ hi,
                                                unsigned short* __restrict__ lo) {
    int i4 = blockIdx.x * 256 + threadIdx.x;     // B*R3*16
    int row = i4 >> 4;
    int b = row >> 15;
    int c0 = (i4 & 15) << 2;
    const float4 x = *(const float4*)(src + ((size_t)i4 << 2));
    float xs[4] = {x.x, x.y, x.z, x.w};
    unsigned short hs[4], ls[4];
#pragma unroll
    for (int j = 0; j < 4; ++j) {
        int c = c0 + j;
        int g = c >> 1;
        float mu = musr[((b << 5) + g) * 2];
        float rstd = musr[((b << 5) + g) * 2 + 1];
        float y = (xs[j] - mu) * rstd * gamma[c] + beta[c];
        y = leaky(y);
        hs[j] = f2bf(y);
        ls[j] = f2bf(y - bf2f(hs[j]));
    }
    ushort4 H; H.x = hs[0]; H.y = hs[1]; H.z = hs[2]; H.w = hs[3];
    ushort4 L; L.x = ls[0]; L.y = ls[1]; L.z = ls[2]; L.w = ls[3];
    *(ushort4*)(hi + ((size_t)i4 << 2)) = H;
    *(ushort4*)(lo + ((size_t)i4 << 2)) = L;
}

// ---------------- conv3d 3x3x3 SAME, 64->64ch, bf16 hi/lo 3-term MFMA
// tile: M=256 voxels (4d x 8h x 8w) x N=64 cout. 4 waves, each 64x64 sub-tile.
// Per tap: stage shifted A(hi,lo) 64KB + W(hi,lo) 16KB via global_load_lds(16B),
// linear LDS + source-pre-swizzle (XOR (row&7)<<4) so ds_read_b128 is conflict-free.
__global__ __launch_bounds__(256, 2) void conv3d_k(
        const unsigned short* __restrict__ Ah, const unsigned short* __restrict__ Al,
        const unsigned short* __restrict__ Wh, const unsigned short* __restrict__ Wl,
        const float* __restrict__ bias, const float* __restrict__ skip,
        float* __restrict__ out, const char* __restrict__ zp) {
    __shared__ __align__(16) unsigned short sAh[16384], sAl[16384], sWh[4096], sWl[4096]; // 80KB
    int tid = threadIdx.x;
    int lane = tid & 63, wave = tid >> 6;
    int wg = blockIdx.x;                       // 1024; XCD-swizzle: one batch per XCD
    int sw = (wg & 7) * 128 + (wg >> 3);
    int b = sw >> 7, t = sw & 127;
    int w0 = (t & 3) << 3, h0 = ((t >> 2) & 3) << 3, d0 = (t >> 4) << 2;

    f32x4 acc[4][4] = {};
    const char* AhB = (const char*)Ah;
    const char* AlB = (const char*)Al;
    const char* WhB = (const char*)Wh;
    const char* WlB = (const char*)Wl;

    for (int ko = 0; ko < 27; ++ko) {
        int di = ko / 9, rem = ko - di * 9, dj = rem / 3, dk = rem - dj * 3;
        __syncthreads();                       // all waves done reading previous tap
        // ---- stage A hi+lo (8 chunks x 1KB/wave each)
#pragma unroll
        for (int i = 0; i < 8; ++i) {
            int X = (i * 256 + tid) << 4;      // linear LDS byte
            int row = X >> 7;                  // voxel row (128B rows)
            int gran = ((X >> 4) & 7) ^ (row & 7);   // source pre-swizzle
            int d = row >> 6, h = (row >> 3) & 7, w = row & 7;
            int gd = d0 + d + di - 1, gh = h0 + h + dj - 1, gw = w0 + w + dk - 1;
            bool ok = ((unsigned)gd < 32u) & ((unsigned)gh < 32u) & ((unsigned)gw < 32u);
            size_t goff = ((((size_t)(b << 15)) +
                            (size_t)((gd << 10) + (gh << 5) + gw)) << 7) + (gran << 4);
            const char* gph = ok ? (AhB + goff) : (zp + (gran << 4));
            const char* gpl = ok ? (AlB + goff) : (zp + (gran << 4));
            int ldsoff = (i * 256 + (wave << 6)) << 4;   // wave-uniform base
            gload_lds16(gph, (char*)sAh + ldsoff);
            gload_lds16(gpl, (char*)sAl + ldsoff);
        }
        // ---- stage W hi+lo (2 chunks each)
#pragma unroll
        for (int i = 0; i < 2; ++i) {
            int X = (i * 256 + tid) << 4;
            int row = X >> 7;                  // cout row
            int gran = ((X >> 4) & 7) ^ (row & 7);
            size_t goff = ((size_t)((ko << 12) + (row << 6) + (gran << 3))) << 1;
            int ldsoff = (i * 256 + (wave << 6)) << 4;
            gload_lds16(WhB + goff, (char*)sWh + ldsoff);
            gload_lds16(WlB + goff, (char*)sWl + ldsoff);
        }
        __syncthreads();                       // vmcnt(0) drained by compiler before barrier
        // ---- compute: 96 MFMA / 32 ds_read_b128 per wave
#pragma unroll
        for (int kh = 0; kh < 2; ++kh) {
            bf16x8 a_h[4], a_l[4], b_h[4], b_l[4];
#pragma unroll
            for (int mf = 0; mf < 4; ++mf) {
                int arow = (wave << 6) + (mf << 4) + (lane & 15);
                int byteoff = (arow << 7) | ((((kh << 2) | (lane >> 4)) ^ (arow & 7)) << 4);
                a_h[mf] = *(const bf16x8*)((const char*)sAh + byteoff);
                a_l[mf] = *(const bf16x8*)((const char*)sAl + byteoff);
            }
#pragma unroll
            for (int nf = 0; nf < 4; ++nf) {
                int brow = (nf << 4) + (lane & 15);
                int byteoff = (brow << 7) | ((((kh << 2) | (lane >> 4)) ^ (brow & 7)) << 4);
                b_h[nf] = *(const bf16x8*)((const char*)sWh + byteoff);
                b_l[nf] = *(const bf16x8*)((const char*)sWl + byteoff);
            }
#pragma unroll
            for (int mf = 0; mf < 4; ++mf)
#pragma unroll
                for (int nf = 0; nf < 4; ++nf) {
                    acc[mf][nf] = __builtin_amdgcn_mfma_f32_16x16x32_bf16(a_h[mf], b_h[nf], acc[mf][nf], 0, 0, 0);
                    acc[mf][nf] = __builtin_amdgcn_mfma_f32_16x16x32_bf16(a_h[mf], b_l[nf], acc[mf][nf], 0, 0, 0);
                    acc[mf][nf] = __builtin_amdgcn_mfma_f32_16x16x32_bf16(a_l[mf], b_h[nf], acc[mf][nf], 0, 0, 0);
                }
        }
    }
    // ---- epilogue: D layout col=lane&15 (cout), row=(lane>>4)*4+reg (voxel)
#pragma unroll
    for (int mf = 0; mf < 4; ++mf) {
#pragma unroll
        for (int nf = 0; nf < 4; ++nf) {
            int co = (nf << 4) + (lane & 15);
            float bv = bias[co];
#pragma unroll
            for (int r = 0; r < 4; ++r) {
                int vrow = (wave << 6) + (mf << 4) + ((lane >> 4) << 2) + r;
                int d = vrow >> 6, h = (vrow >> 3) & 7, w = vrow & 7;
                size_t flat = ((size_t)(b << 15)) +
                              (size_t)(((d0 + d) << 10) + ((h0 + h) << 5) + (w0 + w));
                size_t oi = (flat << 6) + co;
                float v = acc[mf][nf][r] + bv;
                if (skip) v = (v + skip[oi]) * RSQRT2;
                out[oi] = v;
            }
        }
    }
}

// ---------------- fused point MLP + devoxelize + final combine
__global__ __launch_bounds__(256) void point_devox(const float* __restrict__ pts,
                                                   const float* __restrict__ feat,
                                                   const float* __restrict__ w_pi, const float* __restrict__ b_pi,
                                                   const float* __restrict__ w_p1, const float* __restrict__ b_p1,
                                                   const float* __restrict__ w_p2, const float* __restrict__ b_p2,
                                                   const float* __restrict__ grid, float* __restrict__ out) {
    __shared__ float sA[64][64];
    __shared__ float sF0[64][64];
    __shared__ int   sFl[64][8];
    __shared__ float sWt[64][8];
    int tid = threadIdx.x;
    int c = tid & 63, ps = tid >> 6;
    size_t pbase = (size_t)blockIdx.x * 64;
    int b = (int)(pbase >> 15);
#pragma unroll
    for (int i = 0; i < 16; ++i) {
        int p = ps + i * 4;
        sA[p][c] = feat[((pbase + p) << 6) + c];
    }
    if (tid < 64) {
        const float* P = pts + (pbase + tid) * 3;
        int lx, ly, lz; float fx, fy, fz;
        corner_setup(P[0], P[1], P[2], lx, ly, lz, fx, fy, fz);
        int base3 = (lx * 32 + ly) * 32 + lz;
#pragma unroll
        for (int cr = 0; cr < 8; ++cr) {
            int di = cr >> 2, dj = (cr >> 1) & 1, dk = cr & 1;
            sFl[tid][cr] = base3 + di * 1024 + dj * 32 + dk;
            sWt[tid][cr] = (di ? fx : 1.f - fx) * (dj ? fy : 1.f - fy) * (dk ? fz : 1.f - fz);
        }
    }
    __syncthreads();

    float wreg[64], acc[16];
    // ---- layer 1: f0 = feat @ w_pi + b_pi
#pragma unroll
    for (int k = 0; k < 64; ++k) wreg[k] = w_pi[k * 64 + c];
    float bv = b_pi[c];
#pragma unroll
    for (int i = 0; i < 16; ++i) {
        int p = ps + i * 4;
        float a = bv;
#pragma unroll
        for (int k4 = 0; k4 < 16; ++k4) {
            float4 x = *(const float4*)&sA[p][k4 << 2];
            a += x.x * wreg[k4 * 4] + x.y * wreg[k4 * 4 + 1] + x.z * wreg[k4 * 4 + 2] + x.w * wreg[k4 * 4 + 3];
        }
        acc[i] = a;
    }
    __syncthreads();
#pragma unroll
    for (int i = 0; i < 16; ++i) { int p = ps + i * 4; sF0[p][c] = acc[i]; sA[p][c] = leaky(acc[i]); }
    __syncthreads();
    // ---- layer 2
#pragma unroll
    for (int k = 0; k < 64; ++k) wreg[k] = w_p1[k * 64 + c];
    bv = b_p1[c];
#pragma unroll
    for (int i = 0; i < 16; ++i) {
        int p = ps + i * 4;
        float a = bv;
#pragma unroll
        for (int k4 = 0; k4 < 16; ++k4) {
            float4 x = *(const float4*)&sA[p][k4 << 2];
            a += x.x * wreg[k4 * 4] + x.y * wreg[k4 * 4 + 1] + x.z * wreg[k4 * 4 + 2] + x.w * wreg[k4 * 4 + 3];
        }
        acc[i] = a;
    }
    __syncthreads();
#pragma unroll
    for (int i = 0; i < 16; ++i) { int p = ps + i * 4; sA[p][c] = leaky(acc[i]); }
    __syncthreads();
    // ---- layer 3 + point skip
#pragma unroll
    for (int k = 0; k < 64; ++k) wreg[k] = w_p2[k * 64 + c];
    bv = b_p2[c];
#pragma unroll
    for (int i = 0; i < 16; ++i) {
        int p = ps + i * 4;
        float a = bv;
#pragma unroll
        for (int k4 = 0; k4 < 16; ++k4) {
            float4 x = *(const float4*)&sA[p][k4 << 2];
            a += x.x * wreg[k4 * 4] + x.y * wreg[k4 * 4 + 1] + x.z * wreg[k4 * 4 + 2] + x.w * wreg[k4 * 4 + 3];
        }
        acc[i] = (a + sF0[p][c]) * RSQRT2;   // pts
    }
    // ---- devoxelize gather + final combine
    const float* gb = grid + (((size_t)b) << 21);
#pragma unroll
    for (int i = 0; i < 16; ++i) {
        int p = ps + i * 4;
        float dev = 0.f;
#pragma unroll
        for (int cr = 0; cr < 8; ++cr) {
            dev += sWt[p][cr] * gb[(((size_t)sFl[p][cr]) << 6) + c];
        }
        out[((pbase + p) << 6) + c] = (acc[i] + dev) * RSQRT2;
    }
}

// ---------------- workspace layout (bytes) — total ~194 MiB
constexpr size_t OFF_VOX  = 0;                           // f32 [8][32768][64] (normalized)
constexpr size_t OFF_GBUF = 67108864;                    // f32 [8][32768][64]
constexpr size_t OFF_AHI  = OFF_GBUF + 67108864;         // bf16 [8][32768][64]
constexpr size_t OFF_ALO  = OFF_AHI + 33554432;
constexpr size_t OFF_W1H  = OFF_ALO + 33554432;          // bf16 [27][64][64]
constexpr size_t OFF_W1L  = OFF_W1H + 262144;
constexpr size_t OFF_W2H  = OFF_W1L + 262144;
constexpr size_t OFF_W2L  = OFF_W2H + 262144;
constexpr size_t OFF_CS1  = OFF_W2L + 262144;            // f32 [8][64][2]
constexpr size_t OFF_CS2  = OFF_CS1 + 4096;
constexpr size_t OFF_MS1  = OFF_CS2 + 4096;              // f32 [8][32][2]
constexpr size_t OFF_MS2  = OFF_MS1 + 2048;
constexpr size_t OFF_BCNT = OFF_MS2 + 2048;              // int [4096]
constexpr size_t OFF_BSTA = OFF_BCNT + 16384;            // int [4097]
constexpr size_t OFF_BCUR = OFF_BSTA + 20480;            // int [4096]
constexpr size_t OFF_IDX  = OFF_BCUR + 16384;            // int [262144]
constexpr size_t OFF_ZP   = OFF_IDX + 1048576;           // 256B zeros
constexpr size_t OFF_END  = OFF_ZP + 256;

extern "C" void kernel_launch(void* const* d_in, const int* in_sizes, int n_in,
                              void* d_out, int out_size, void* d_ws, size_t ws_size,
                              hipStream_t stream) {
    const float* points = (const float*)d_in[0];
    const float* feat   = (const float*)d_in[1];
    const float* w_pi = (const float*)d_in[2];
    const float* b_pi = (const float*)d_in[3];
    const float* w_p1 = (const float*)d_in[4];
    const float* b_p1 = (const float*)d_in[5];
    const float* w_p2 = (const float*)d_in[6];
    const float* b_p2 = (const float*)d_in[7];
    const float* g1   = (const float*)d_in[8];
    const float* be1  = (const float*)d_in[9];
    const float* w_c1 = (const float*)d_in[10];
    const float* b_c1 = (const float*)d_in[11];
    const float* g2   = (const float*)d_in[12];
    const float* be2  = (const float*)d_in[13];
    const float* w_c2 = (const float*)d_in[14];
    const float* b_c2 = (const float*)d_in[15];

    char* ws = (char*)d_ws;
    float* vox  = (float*)(ws + OFF_VOX);
    float* gbuf = (float*)(ws + OFF_GBUF);
    unsigned short* ahi = (unsigned short*)(ws + OFF_AHI);
    unsigned short* alo = (unsigned short*)(ws + OFF_ALO);
    unsigned short* w1h = (unsigned short*)(ws + OFF_W1H);
    unsigned short* w1l = (unsigned short*)(ws + OFF_W1L);
    unsigned short* w2h = (unsigned short*)(ws + OFF_W2H);
    unsigned short* w2l = (unsigned short*)(ws + OFF_W2L);
    float* cs1 = (float*)(ws + OFF_CS1);
    float* cs2 = (float*)(ws + OFF_CS2);
    float* ms1 = (float*)(ws + OFF_MS1);
    float* ms2 = (float*)(ws + OFF_MS2);
    int* bcnt = (int*)(ws + OFF_BCNT);
    int* bsta = (int*)(ws + OFF_BSTA);
    int* bcur = (int*)(ws + OFF_BCUR);
    int* idxb = (int*)(ws + OFF_IDX);
    char* zp  = ws + OFF_ZP;

    // zero: stat buffers + bin counts + zero page (everything else fully written)
    hipMemsetAsync(ws + OFF_CS1, 0, 12288, stream);
    hipMemsetAsync(ws + OFF_BCNT, 0, 16384, stream);
    hipMemsetAsync(ws + OFF_ZP, 0, 256, stream);

    wt_transform<<<432, 256, 0, stream>>>(w_c1, w1h, w1l);
    wt_transform<<<432, 256, 0, stream>>>(w_c2, w2h, w2l);

    bin_count<<<1024, 256, 0, stream>>>(points, bcnt);
    bin_scan<<<1, 256, 0, stream>>>(bcnt, bsta, bcur);
    bin_fill<<<1024, 256, 0, stream>>>(points, bcur, idxb);
    vox_accum<<<4096, 256, 0, stream>>>(points, feat, bsta, idxb, vox, cs1);

    gn_finalize<<<1, 256, 0, stream>>>(cs1, ms1);
    gn_apply<<<16384, 256, 0, stream>>>(vox, ms1, g1, be1, ahi, alo);
    conv3d_k<<<1024, 256, 0, stream>>>(ahi, alo, w1h, w1l, b_c1, nullptr, gbuf, zp);

    norm_stats<<<dim3(128, 8), 256, 0, stream>>>(gbuf, cs2);
    gn_finalize<<<1, 256, 0, stream>>>(cs2, ms2);
    gn_apply<<<16384, 256, 0, stream>>>(gbuf, ms2, g2, be2, ahi, alo);
    conv3d_k<<<1024, 256, 0, stream>>>(ahi, alo, w2h, w2l, b_c2, vox, gbuf, zp);

    point_devox<<<4096, 256, 0, stream>>>(points, feat, w_pi, b_pi, w_p1, b_p1,
                                          w_p2, b_p2, gbuf, (float*)d_out);
}

// Round 3
// 1481.615 us; speedup vs baseline: 2.4897x; 1.5168x over previous
//
#include <hip/hip_runtime.h>

// PointVoxelCNN fused pipeline for MI355X (gfx950).
// B=8, N=32768, C=Cin=64, R=32, G=32 (2 channels/group).
// Round 3: point branch rebuilt. point_mlp = MFMA bf16 hi/lo 3-layer GEMM
// (256-pt tiles, LDS-transposed activations); devox_combine = lean high-occupancy
// gather kernel. Voxel branch (conv3d_k etc.) unchanged from round 2.

#define RSQRT2 0.70710678118654752440f

typedef float f32x4 __attribute__((ext_vector_type(4)));
typedef __bf16 bf16x8 __attribute__((ext_vector_type(8)));

static __device__ __forceinline__ unsigned short f2bf(float x) {
    union { float f; unsigned u; } v; v.f = x;
    unsigned r = v.u + 0x7FFFu + ((v.u >> 16) & 1u);
    return (unsigned short)(r >> 16);
}
static __device__ __forceinline__ float bf2f(unsigned short b) {
    union { unsigned u; float f; } v; v.u = ((unsigned)b) << 16; return v.f;
}
static __device__ __forceinline__ float leaky(float x) { return x >= 0.f ? x : 0.01f * x; }

static __device__ __forceinline__ void gload_lds16(const void* g, void* l) {
    __builtin_amdgcn_global_load_lds(
        (const __attribute__((address_space(1))) unsigned int*)g,
        (__attribute__((address_space(3))) unsigned int*)l, 16, 0, 0);
}

static __device__ __forceinline__ void corner_setup(float px, float py, float pz,
        int& lx, int& ly, int& lz, float& fx, float& fy, float& fz) {
    float cx = fminf(fmaxf((px + 1.f) * 15.5f, 0.f), 31.f);
    float cy = fminf(fmaxf((py + 1.f) * 15.5f, 0.f), 31.f);
    float cz = fminf(fmaxf((pz + 1.f) * 15.5f, 0.f), 31.f);
    lx = (int)cx; if (lx > 30) lx = 30; fx = cx - (float)lx;
    ly = (int)cy; if (ly > 30) ly = 30; fy = cy - (float)ly;
    lz = (int)cz; if (lz > 30) lz = 30; fz = cz - (float)lz;
}

// ---------------- weight transform: w[O][I][27] f32 -> wt[ko][co][ci] bf16 hi/lo
__global__ __launch_bounds__(256) void wt_transform(const float* __restrict__ w,
                                                    unsigned short* __restrict__ hi,
                                                    unsigned short* __restrict__ lo) {
    int idx = blockIdx.x * 256 + threadIdx.x;    // 27*64*64 = 110592
    int ko = idx >> 12;
    int co = (idx >> 6) & 63;
    int ci = idx & 63;
    float v = w[(co * 64 + ci) * 27 + ko];
    unsigned short h = f2bf(v);
    hi[idx] = h;
    lo[idx] = f2bf(v - bf2f(h));
}

// ---------------- MLP weight transform: w[ci][co] f32 -> wm[L][co][ci] bf16 hi/lo
__global__ __launch_bounds__(256) void mlp_wt(const float* __restrict__ w0,
                                              const float* __restrict__ w1,
                                              const float* __restrict__ w2,
                                              unsigned short* __restrict__ hi,
                                              unsigned short* __restrict__ lo) {
    int idx = blockIdx.x * 256 + threadIdx.x;    // 48*256 = 12288
    int L = idx >> 12, rem = idx & 4095;
    int co = rem >> 6, ci = rem & 63;
    const float* s = (L == 0) ? w0 : (L == 1) ? w1 : w2;
    float v = s[ci * 64 + co];
    unsigned short h = f2bf(v);
    hi[idx] = h;
    lo[idx] = f2bf(v - bf2f(h));
}

// ---------------- voxelize pass 1: count points per 4x4x4 bin
__global__ __launch_bounds__(256) void bin_count(const float* __restrict__ pts,
                                                 int* __restrict__ cnt) {
    int p = blockIdx.x * 256 + threadIdx.x;      // 262144
    int lx, ly, lz; float fx, fy, fz;
    corner_setup(pts[p * 3], pts[p * 3 + 1], pts[p * 3 + 2], lx, ly, lz, fx, fy, fz);
    int b = p >> 15;
    int bin = (b << 9) | ((lx >> 2) << 6) | ((ly >> 2) << 3) | (lz >> 2);
    atomicAdd(&cnt[bin], 1);
}

// ---------------- voxelize pass 2: exclusive scan of 4096 bins (1 block)
__global__ __launch_bounds__(256) void bin_scan(const int* __restrict__ cnt,
                                                int* __restrict__ start,
                                                int* __restrict__ cursor) {
    __shared__ int part[256];
    int t = threadIdx.x;
    int local[16];
    int s = 0;
#pragma unroll
    for (int i = 0; i < 16; ++i) { local[i] = s; s += cnt[t * 16 + i]; }
    part[t] = s;
    __syncthreads();
    for (int off = 1; off < 256; off <<= 1) {
        int v = (t >= off) ? part[t - off] : 0;
        __syncthreads();
        part[t] += v;
        __syncthreads();
    }
    int base = (t == 0) ? 0 : part[t - 1];
#pragma unroll
    for (int i = 0; i < 16; ++i) {
        int v = base + local[i];
        start[t * 16 + i] = v;
        cursor[t * 16 + i] = v;
    }
    if (t == 255) start[4096] = part[255];
}

// ---------------- voxelize pass 3: scatter point indices into bins
__global__ __launch_bounds__(256) void bin_fill(const float* __restrict__ pts,
                                                int* __restrict__ cursor,
                                                int* __restrict__ idxb) {
    int p = blockIdx.x * 256 + threadIdx.x;
    int lx, ly, lz; float fx, fy, fz;
    corner_setup(pts[p * 3], pts[p * 3 + 1], pts[p * 3 + 2], lx, ly, lz, fx, fy, fz);
    int b = p >> 15;
    int bin = (b << 9) | ((lx >> 2) << 6) | ((ly >> 2) << 3) | (lz >> 2);
    int slot = atomicAdd(&cursor[bin], 1);
    idxb[slot] = p;
}

// ---------------- voxelize pass 4: region-exclusive accumulate + normalize + GN1 stats
__global__ __launch_bounds__(256) void vox_accum(const float* __restrict__ pts,
                                                 const float* __restrict__ feat,
                                                 const int* __restrict__ start,
                                                 const int* __restrict__ idxb,
                                                 float* __restrict__ vox,
                                                 float* __restrict__ chsum) {
    __shared__ float acc[4096];      // [cell 64][ch 64]
    __shared__ float cw[64];
    __shared__ float rs[256], rq[256];
    int tid = threadIdx.x, lane = tid & 63, wv = tid >> 6;
    int gid = blockIdx.x;            // 4096 = b*512 + r3
    int b = gid >> 9, r3 = gid & 511;
    int rx = r3 >> 6, ry = (r3 >> 3) & 7, rz = r3 & 7;
    int cx0 = rx << 2, cy0 = ry << 2, cz0 = rz << 2;
    for (int i = tid; i < 4096; i += 256) acc[i] = 0.f;
    if (tid < 64) cw[tid] = 0.f;
    __syncthreads();

    for (int nb = 0; nb < 8; ++nb) {
        int bx = rx - 1 + (nb >> 2), by = ry - 1 + ((nb >> 1) & 1), bz = rz - 1 + (nb & 1);
        if (((unsigned)bx > 7u) || ((unsigned)by > 7u) || ((unsigned)bz > 7u)) continue;
        int bin = (b << 9) | (bx << 6) | (by << 3) | bz;
        int s0 = start[bin], s1 = start[bin + 1];
        for (int i = s0 + wv; i < s1; i += 4) {     // waves stripe the bin's points
            int p = idxb[i];
            int lx, ly, lz; float fx, fy, fz;
            corner_setup(pts[p * 3], pts[p * 3 + 1], pts[p * 3 + 2], lx, ly, lz, fx, fy, fz);
            float f = feat[((size_t)p << 6) + lane];
#pragma unroll
            for (int cr = 0; cr < 8; ++cr) {
                int ux = lx + (cr >> 2) - cx0;
                int uy = ly + ((cr >> 1) & 1) - cy0;
                int uz = lz + (cr & 1) - cz0;
                if (((unsigned)ux < 4u) && ((unsigned)uy < 4u) && ((unsigned)uz < 4u)) {
                    float w = ((cr & 4) ? fx : 1.f - fx) * ((cr & 2) ? fy : 1.f - fy)
                            * ((cr & 1) ? fz : 1.f - fz);
                    int cl = (ux << 4) | (uy << 2) | uz;
                    atomicAdd(&acc[(cl << 6) | lane], w * f);
                    if (lane == 0) atomicAdd(&cw[cl], w);
                }
            }
        }
    }
    __syncthreads();
    // normalize + write + per-channel partial sums
    float s = 0.f, q = 0.f;
    for (int c = wv; c < 64; c += 4) {
        float v = acc[(c << 6) | lane] / fmaxf(cw[c], 1e-8f);
        int cxx = cx0 + (c >> 4), cyy = cy0 + ((c >> 2) & 3), czz = cz0 + (c & 3);
        size_t flat = ((size_t)(b << 15)) + (size_t)((cxx << 10) | (cyy << 5) | czz);
        vox[(flat << 6) + lane] = v;
        s += v; q += v * v;
    }
    rs[tid] = s; rq[tid] = q;
    __syncthreads();
    if (tid < 64) {
        s = rs[tid] + rs[tid + 64] + rs[tid + 128] + rs[tid + 192];
        q = rq[tid] + rq[tid + 64] + rq[tid + 128] + rq[tid + 192];
        atomicAdd(&chsum[((b << 6) + tid) * 2], s);
        atomicAdd(&chsum[((b << 6) + tid) * 2 + 1], q);
    }
}

// ---------------- per-channel partial sums for GN2 (reads conv1 output)
__global__ __launch_bounds__(256) void norm_stats(const float* __restrict__ src,
                                                  float* __restrict__ chsum) {
    __shared__ float rs[256], rq[256];
    int b = blockIdx.y;
    int tid = threadIdx.x;
    int c = tid & 63, rsub = tid >> 6;
    size_t rowb = ((size_t)b << 15) + (size_t)blockIdx.x * 256;
    float s = 0.f, q = 0.f;
    for (int i = 0; i < 64; ++i) {
        size_t idx = ((rowb + rsub + i * 4) << 6) + c;
        float v = src[idx];
        s += v; q += v * v;
    }
    rs[tid] = s; rq[tid] = q;
    __syncthreads();
    if (tid < 64) {
        s = rs[tid] + rs[tid + 64] + rs[tid + 128] + rs[tid + 192];
        q = rq[tid] + rq[tid + 64] + rq[tid + 128] + rq[tid + 192];
        atomicAdd(&chsum[((b << 6) + tid) * 2], s);
        atomicAdd(&chsum[((b << 6) + tid) * 2 + 1], q);
    }
}

// ---------------- finalize GN stats: chsum[b][64][2] -> musr[b][32][2] (mu, rstd)
__global__ void gn_finalize(const float* __restrict__ chsum, float* __restrict__ musr) {
    int t = threadIdx.x;              // 256 = 8 b * 32 g
    int b = t >> 5, g = t & 31;
    float s = chsum[((b << 6) + 2 * g) * 2] + chsum[((b << 6) + 2 * g + 1) * 2];
    float q = chsum[((b << 6) + 2 * g) * 2 + 1] + chsum[((b << 6) + 2 * g + 1) * 2 + 1];
    float mu = s * (1.f / 65536.f);
    float var = q * (1.f / 65536.f) - mu * mu;
    musr[t * 2] = mu;
    musr[t * 2 + 1] = rsqrtf(var + 1e-5f);
}

// ---------------- GN apply + leaky -> bf16 hi/lo activation planes
__global__ __launch_bounds__(256) void gn_apply(const float* __restrict__ src,
                                                const float* __restrict__ musr,
                                                const float* __restrict__ gamma,
                                                const float* __restrict__ beta,
                                                unsigned short* __restrict__ hi,
                                                unsigned short* __restrict__ lo) {
    int i4 = blockIdx.x * 256 + threadIdx.x;     // B*R3*16
    int row = i4 >> 4;
    int b = row >> 15;
    int c0 = (i4 & 15) << 2;
    const float4 x = *(const float4*)(src + ((size_t)i4 << 2));
    float xs[4] = {x.x, x.y, x.z, x.w};
    unsigned short hs[4], ls[4];
#pragma unroll
    for (int j = 0; j < 4; ++j) {
        int c = c0 + j;
        int g = c >> 1;
        float mu = musr[((b << 5) + g) * 2];
        float rstd = musr[((b << 5) + g) * 2 + 1];
        float y = (xs[j] - mu) * rstd * gamma[c] + beta[c];
        y = leaky(y);
        hs[j] = f2bf(y);
        ls[j] = f2bf(y - bf2f(hs[j]));
    }
    ushort4 H; H.x = hs[0]; H.y = hs[1]; H.z = hs[2]; H.w = hs[3];
    ushort4 L; L.x = ls[0]; L.y = ls[1]; L.z = ls[2]; L.w = ls[3];
    *(ushort4*)(hi + ((size_t)i4 << 2)) = H;
    *(ushort4*)(lo + ((size_t)i4 << 2)) = L;
}

// ---------------- conv3d 3x3x3 SAME, 64->64ch, bf16 hi/lo 3-term MFMA
__global__ __launch_bounds__(256, 2) void conv3d_k(
        const unsigned short* __restrict__ Ah, const unsigned short* __restrict__ Al,
        const unsigned short* __restrict__ Wh, const unsigned short* __restrict__ Wl,
        const float* __restrict__ bias, const float* __restrict__ skip,
        float* __restrict__ out, const char* __restrict__ zp) {
    __shared__ __align__(16) unsigned short sAh[16384], sAl[16384], sWh[4096], sWl[4096]; // 80KB
    int tid = threadIdx.x;
    int lane = tid & 63, wave = tid >> 6;
    int wg = blockIdx.x;                       // 1024; XCD-swizzle: one batch per XCD
    int sw = (wg & 7) * 128 + (wg >> 3);
    int b = sw >> 7, t = sw & 127;
    int w0 = (t & 3) << 3, h0 = ((t >> 2) & 3) << 3, d0 = (t >> 4) << 2;

    f32x4 acc[4][4] = {};
    const char* AhB = (const char*)Ah;
    const char* AlB = (const char*)Al;
    const char* WhB = (const char*)Wh;
    const char* WlB = (const char*)Wl;

    for (int ko = 0; ko < 27; ++ko) {
        int di = ko / 9, rem = ko - di * 9, dj = rem / 3, dk = rem - dj * 3;
        __syncthreads();                       // all waves done reading previous tap
        // ---- stage A hi+lo
#pragma unroll
        for (int i = 0; i < 8; ++i) {
            int X = (i * 256 + tid) << 4;      // linear LDS byte
            int row = X >> 7;                  // voxel row (128B rows)
            int gran = ((X >> 4) & 7) ^ (row & 7);   // source pre-swizzle
            int d = row >> 6, h = (row >> 3) & 7, w = row & 7;
            int gd = d0 + d + di - 1, gh = h0 + h + dj - 1, gw = w0 + w + dk - 1;
            bool ok = ((unsigned)gd < 32u) & ((unsigned)gh < 32u) & ((unsigned)gw < 32u);
            size_t goff = ((((size_t)(b << 15)) +
                            (size_t)((gd << 10) + (gh << 5) + gw)) << 7) + (gran << 4);
            const char* gph = ok ? (AhB + goff) : (zp + (gran << 4));
            const char* gpl = ok ? (AlB + goff) : (zp + (gran << 4));
            int ldsoff = (i * 256 + (wave << 6)) << 4;   // wave-uniform base
            gload_lds16(gph, (char*)sAh + ldsoff);
            gload_lds16(gpl, (char*)sAl + ldsoff);
        }
        // ---- stage W hi+lo
#pragma unroll
        for (int i = 0; i < 2; ++i) {
            int X = (i * 256 + tid) << 4;
            int row = X >> 7;                  // cout row
            int gran = ((X >> 4) & 7) ^ (row & 7);
            size_t goff = ((size_t)((ko << 12) + (row << 6) + (gran << 3))) << 1;
            int ldsoff = (i * 256 + (wave << 6)) << 4;
            gload_lds16(WhB + goff, (char*)sWh + ldsoff);
            gload_lds16(WlB + goff, (char*)sWl + ldsoff);
        }
        __syncthreads();
        // ---- compute
#pragma unroll
        for (int kh = 0; kh < 2; ++kh) {
            bf16x8 a_h[4], a_l[4], b_h[4], b_l[4];
#pragma unroll
            for (int mf = 0; mf < 4; ++mf) {
                int arow = (wave << 6) + (mf << 4) + (lane & 15);
                int byteoff = (arow << 7) | ((((kh << 2) | (lane >> 4)) ^ (arow & 7)) << 4);
                a_h[mf] = *(const bf16x8*)((const char*)sAh + byteoff);
                a_l[mf] = *(const bf16x8*)((const char*)sAl + byteoff);
            }
#pragma unroll
            for (int nf = 0; nf < 4; ++nf) {
                int brow = (nf << 4) + (lane & 15);
                int byteoff = (brow << 7) | ((((kh << 2) | (lane >> 4)) ^ (brow & 7)) << 4);
                b_h[nf] = *(const bf16x8*)((const char*)sWh + byteoff);
                b_l[nf] = *(const bf16x8*)((const char*)sWl + byteoff);
            }
#pragma unroll
            for (int mf = 0; mf < 4; ++mf)
#pragma unroll
                for (int nf = 0; nf < 4; ++nf) {
                    acc[mf][nf] = __builtin_amdgcn_mfma_f32_16x16x32_bf16(a_h[mf], b_h[nf], acc[mf][nf], 0, 0, 0);
                    acc[mf][nf] = __builtin_amdgcn_mfma_f32_16x16x32_bf16(a_h[mf], b_l[nf], acc[mf][nf], 0, 0, 0);
                    acc[mf][nf] = __builtin_amdgcn_mfma_f32_16x16x32_bf16(a_l[mf], b_h[nf], acc[mf][nf], 0, 0, 0);
                }
        }
    }
    // ---- epilogue
#pragma unroll
    for (int mf = 0; mf < 4; ++mf) {
#pragma unroll
        for (int nf = 0; nf < 4; ++nf) {
            int co = (nf << 4) + (lane & 15);
            float bv = bias[co];
#pragma unroll
            for (int r = 0; r < 4; ++r) {
                int vrow = (wave << 6) + (mf << 4) + ((lane >> 4) << 2) + r;
                int d = vrow >> 6, h = (vrow >> 3) & 7, w = vrow & 7;
                size_t flat = ((size_t)(b << 15)) +
                              (size_t)(((d0 + d) << 10) + ((h0 + h) << 5) + (w0 + w));
                size_t oi = (flat << 6) + co;
                float v = acc[mf][nf][r] + bv;
                if (skip) v = (v + skip[oi]) * RSQRT2;
                out[oi] = v;
            }
        }
    }
}

// ---------------- point MLP: 3x (64x64 GEMM) via MFMA bf16 hi/lo, 256 pts/block
__global__ __launch_bounds__(256, 2) void point_mlp(
        const float* __restrict__ feat,
        const unsigned short* __restrict__ Mh, const unsigned short* __restrict__ Ml,
        const float* __restrict__ b0, const float* __restrict__ b1,
        const float* __restrict__ b2, float* __restrict__ pout) {
    __shared__ __align__(16) unsigned short sAh[16384], sAl[16384], sWh[4096], sWl[4096]; // 80KB
    int tid = threadIdx.x, lane = tid & 63, wave = tid >> 6;
    size_t pbase = (size_t)blockIdx.x << 8;

    // stage A: feat fp32 -> bf16 hi/lo, swizzled (rows = points, 128B rows)
    const float4* f4 = (const float4*)(feat + (pbase << 6));
#pragma unroll
    for (int j = 0; j < 16; ++j) {
        int fidx = j * 256 + tid;
        float4 v = f4[fidx];
        float vv[4] = {v.x, v.y, v.z, v.w};
        unsigned short hh[4], ll[4];
#pragma unroll
        for (int k = 0; k < 4; ++k) { hh[k] = f2bf(vv[k]); ll[k] = f2bf(vv[k] - bf2f(hh[k])); }
        ushort4 H; H.x = hh[0]; H.y = hh[1]; H.z = hh[2]; H.w = hh[3];
        ushort4 Lo; Lo.x = ll[0]; Lo.y = ll[1]; Lo.z = ll[2]; Lo.w = ll[3];
        int Xb = fidx << 3;                    // byte offset in bf16 A-plane
        int row = Xb >> 7;
        int dest = (row << 7) | ((((Xb >> 4) & 7) ^ (row & 7)) << 4) | (Xb & 8);
        *(ushort4*)((char*)sAh + dest) = H;
        *(ushort4*)((char*)sAl + dest) = Lo;
    }

    f32x4 f0[4][4];
#pragma unroll
    for (int L = 0; L < 3; ++L) {
        __syncthreads();                       // A/act writes visible; sW free
        // stage W layer L (pre-swizzled source, linear LDS dest)
#pragma unroll
        for (int i = 0; i < 2; ++i) {
            int X = (i * 256 + tid) << 4;
            int row = X >> 7;
            int gran = ((X >> 4) & 7) ^ (row & 7);
            size_t goff = ((size_t)((L << 12) + (row << 6) + (gran << 3))) << 1;
            int ldsoff = (i * 256 + (wave << 6)) << 4;
            gload_lds16((const char*)Mh + goff, (char*)sWh + ldsoff);
            gload_lds16((const char*)Ml + goff, (char*)sWl + ldsoff);
        }
        __syncthreads();
        f32x4 acc[4][4] = {};
#pragma unroll
        for (int kh = 0; kh < 2; ++kh) {
            bf16x8 a_h[4], a_l[4], b_h[4], b_l[4];
#pragma unroll
            for (int mf = 0; mf < 4; ++mf) {
                int arow = (wave << 6) + (mf << 4) + (lane & 15);
                int byteoff = (arow << 7) | ((((kh << 2) | (lane >> 4)) ^ (arow & 7)) << 4);
                a_h[mf] = *(const bf16x8*)((const char*)sAh + byteoff);
                a_l[mf] = *(const bf16x8*)((const char*)sAl + byteoff);
            }
#pragma unroll
            for (int nf = 0; nf < 4; ++nf) {
                int brow = (nf << 4) + (lane & 15);
                int byteoff = (brow << 7) | ((((kh << 2) | (lane >> 4)) ^ (brow & 7)) << 4);
                b_h[nf] = *(const bf16x8*)((const char*)sWh + byteoff);
                b_l[nf] = *(const bf16x8*)((const char*)sWl + byteoff);
            }
#pragma unroll
            for (int mf = 0; mf < 4; ++mf)
#pragma unroll
                for (int nf = 0; nf < 4; ++nf) {
                    acc[mf][nf] = __builtin_amdgcn_mfma_f32_16x16x32_bf16(a_h[mf], b_h[nf], acc[mf][nf], 0, 0, 0);
                    acc[mf][nf] = __builtin_amdgcn_mfma_f32_16x16x32_bf16(a_h[mf], b_l[nf], acc[mf][nf], 0, 0, 0);
                    acc[mf][nf] = __builtin_amdgcn_mfma_f32_16x16x32_bf16(a_l[mf], b_h[nf], acc[mf][nf], 0, 0, 0);
                }
        }
        const float* bp = (L == 0) ? b0 : (L == 1) ? b1 : b2;
        if (L < 2) {
            __syncthreads();                   // all waves done reading sA this layer
#pragma unroll
            for (int nf = 0; nf < 4; ++nf) {
                int col = (nf << 4) + (lane & 15);
                float bv = bp[col];
#pragma unroll
                for (int mf = 0; mf < 4; ++mf)
#pragma unroll
                    for (int r = 0; r < 4; ++r) {
                        float v = acc[mf][nf][r] + bv;
                        if (L == 0) f0[mf][nf][r] = v;
                        float a = leaky(v);
                        unsigned short h = f2bf(a);
                        unsigned short l = f2bf(a - bf2f(h));
                        int row = (wave << 6) + (mf << 4) + ((lane >> 4) << 2) + r;
                        int dest = (row << 7) | (((col >> 3) ^ (row & 7)) << 4) | ((col << 1) & 15);
                        *(unsigned short*)((char*)sAh + dest) = h;
                        *(unsigned short*)((char*)sAl + dest) = l;
                    }
            }
        } else {
#pragma unroll
            for (int nf = 0; nf < 4; ++nf) {
                int col = (nf << 4) + (lane & 15);
                float bv = bp[col];
#pragma unroll
                for (int mf = 0; mf < 4; ++mf)
#pragma unroll
                    for (int r = 0; r < 4; ++r) {
                        int row = (wave << 6) + (mf << 4) + ((lane >> 4) << 2) + r;
                        float v = (acc[mf][nf][r] + bv + f0[mf][nf][r]) * RSQRT2;
                        pout[((pbase + row) << 6) + col] = v;
                    }
            }
        }
    }
}

// ---------------- devoxelize gather + final combine (lean, high-occupancy)
__global__ __launch_bounds__(256, 8) void devox_combine(
        const float* __restrict__ pts, const float* __restrict__ pmlp,
        const float* __restrict__ grid, float* __restrict__ out) {
    __shared__ int   sFl[64][8];
    __shared__ float sWt[64][8];
    int tid = threadIdx.x;
    size_t pbase = (size_t)blockIdx.x << 6;
    int b = (int)(pbase >> 15);
    if (tid < 64) {
        const float* P = pts + (pbase + tid) * 3;
        int lx, ly, lz; float fx, fy, fz;
        corner_setup(P[0], P[1], P[2], lx, ly, lz, fx, fy, fz);
        int base3 = (lx << 10) + (ly << 5) + lz;
#pragma unroll
        for (int cr = 0; cr < 8; ++cr) {
            sFl[tid][cr] = base3 + (cr >> 2) * 1024 + ((cr >> 1) & 1) * 32 + (cr & 1);
            sWt[tid][cr] = ((cr & 4) ? fx : 1.f - fx) * ((cr & 2) ? fy : 1.f - fy)
                         * ((cr & 1) ? fz : 1.f - fz);
        }
    }
    __syncthreads();
    int c = tid & 63, wv = tid >> 6;
    const float* gb = grid + (((size_t)b) << 21);
#pragma unroll 4
    for (int i = 0; i < 16; ++i) {
        int p = (wv << 4) + i;                 // whole wave shares p -> LDS broadcast
        float dev = 0.f;
#pragma unroll
        for (int cr = 0; cr < 8; ++cr)
            dev += sWt[p][cr] * gb[(((size_t)sFl[p][cr]) << 6) + c];
        size_t oi = ((pbase + p) << 6) + c;
        out[oi] = (pmlp[oi] + dev) * RSQRT2;
    }
}

// ---------------- workspace layout (bytes)
constexpr size_t OFF_VOX  = 0;                           // f32 [8][32768][64] (normalized)
constexpr size_t OFF_GBUF = 67108864;                    // f32 [8][32768][64]
constexpr size_t OFF_AHI  = OFF_GBUF + 67108864;         // bf16 staging; later pmlp f32 (64MB)
constexpr size_t OFF_ALO  = OFF_AHI + 33554432;
constexpr size_t OFF_W1H  = OFF_ALO + 33554432;          // bf16 [27][64][64]
constexpr size_t OFF_W1L  = OFF_W1H + 262144;
constexpr size_t OFF_W2H  = OFF_W1L + 262144;
constexpr size_t OFF_W2L  = OFF_W2H + 262144;
constexpr size_t OFF_CS1  = OFF_W2L + 262144;            // f32 [8][64][2]
constexpr size_t OFF_CS2  = OFF_CS1 + 4096;
constexpr size_t OFF_MS1  = OFF_CS2 + 4096;              // f32 [8][32][2]
constexpr size_t OFF_MS2  = OFF_MS1 + 2048;
constexpr size_t OFF_BCNT = OFF_MS2 + 2048;              // int [4096]
constexpr size_t OFF_BSTA = OFF_BCNT + 16384;            // int [4097]
constexpr size_t OFF_BCUR = OFF_BSTA + 20480;            // int [4096]
constexpr size_t OFF_IDX  = OFF_BCUR + 16384;            // int [262144]
constexpr size_t OFF_ZP   = OFF_IDX + 1048576;           // 256B zeros
constexpr size_t OFF_MWH  = OFF_ZP + 256;                // bf16 [3][64][64]
constexpr size_t OFF_MWL  = OFF_MWH + 24576;
constexpr size_t OFF_END  = OFF_MWL + 24576;

extern "C" void kernel_launch(void* const* d_in, const int* in_sizes, int n_in,
                              void* d_out, int out_size, void* d_ws, size_t ws_size,
                              hipStream_t stream) {
    const float* points = (const float*)d_in[0];
    const float* feat   = (const float*)d_in[1];
    const float* w_pi = (const float*)d_in[2];
    const float* b_pi = (const float*)d_in[3];
    const float* w_p1 = (const float*)d_in[4];
    const float* b_p1 = (const float*)d_in[5];
    const float* w_p2 = (const float*)d_in[6];
    const float* b_p2 = (const float*)d_in[7];
    const float* g1   = (const float*)d_in[8];
    const float* be1  = (const float*)d_in[9];
    const float* w_c1 = (const float*)d_in[10];
    const float* b_c1 = (const float*)d_in[11];
    const float* g2   = (const float*)d_in[12];
    const float* be2  = (const float*)d_in[13];
    const float* w_c2 = (const float*)d_in[14];
    const float* b_c2 = (const float*)d_in[15];

    char* ws = (char*)d_ws;
    float* vox  = (float*)(ws + OFF_VOX);
    float* gbuf = (float*)(ws + OFF_GBUF);
    unsigned short* ahi = (unsigned short*)(ws + OFF_AHI);
    unsigned short* alo = (unsigned short*)(ws + OFF_ALO);
    float* pmlp = (float*)(ws + OFF_AHI);      // reuses ahi+alo after conv2
    unsigned short* w1h = (unsigned short*)(ws + OFF_W1H);
    unsigned short* w1l = (unsigned short*)(ws + OFF_W1L);
    unsigned short* w2h = (unsigned short*)(ws + OFF_W2H);
    unsigned short* w2l = (unsigned short*)(ws + OFF_W2L);
    float* cs1 = (float*)(ws + OFF_CS1);
    float* cs2 = (float*)(ws + OFF_CS2);
    float* ms1 = (float*)(ws + OFF_MS1);
    float* ms2 = (float*)(ws + OFF_MS2);
    int* bcnt = (int*)(ws + OFF_BCNT);
    int* bsta = (int*)(ws + OFF_BSTA);
    int* bcur = (int*)(ws + OFF_BCUR);
    int* idxb = (int*)(ws + OFF_IDX);
    char* zp  = ws + OFF_ZP;
    unsigned short* mwh = (unsigned short*)(ws + OFF_MWH);
    unsigned short* mwl = (unsigned short*)(ws + OFF_MWL);

    hipMemsetAsync(ws + OFF_CS1, 0, 12288, stream);
    hipMemsetAsync(ws + OFF_BCNT, 0, 16384, stream);
    hipMemsetAsync(ws + OFF_ZP, 0, 256, stream);

    wt_transform<<<432, 256, 0, stream>>>(w_c1, w1h, w1l);
    wt_transform<<<432, 256, 0, stream>>>(w_c2, w2h, w2l);
    mlp_wt<<<48, 256, 0, stream>>>(w_pi, w_p1, w_p2, mwh, mwl);

    bin_count<<<1024, 256, 0, stream>>>(points, bcnt);
    bin_scan<<<1, 256, 0, stream>>>(bcnt, bsta, bcur);
    bin_fill<<<1024, 256, 0, stream>>>(points, bcur, idxb);
    vox_accum<<<4096, 256, 0, stream>>>(points, feat, bsta, idxb, vox, cs1);

    gn_finalize<<<1, 256, 0, stream>>>(cs1, ms1);
    gn_apply<<<16384, 256, 0, stream>>>(vox, ms1, g1, be1, ahi, alo);
    conv3d_k<<<1024, 256, 0, stream>>>(ahi, alo, w1h, w1l, b_c1, nullptr, gbuf, zp);

    norm_stats<<<dim3(128, 8), 256, 0, stream>>>(gbuf, cs2);
    gn_finalize<<<1, 256, 0, stream>>>(cs2, ms2);
    gn_apply<<<16384, 256, 0, stream>>>(gbuf, ms2, g2, be2, ahi, alo);
    conv3d_k<<<1024, 256, 0, stream>>>(ahi, alo, w2h, w2l, b_c2, vox, gbuf, zp);

    point_mlp<<<1024, 256, 0, stream>>>(feat, mwh, mwl, b_pi, b_p1, b_p2, pmlp);
    devox_combine<<<4096, 256, 0, stream>>>(points, pmlp, gbuf, (float*)d_out);
}